// Round 7
// baseline (162.854 us; speedup 1.0000x reference)
//
#include <hip/hip_runtime.h>

// B=4, N=4096, D=128 fixed by the reference setup.
// d_ws layout: [0, 4MiB) h as bf16 bits (ushort), [4MiB, +64KiB) sq fp32.

typedef float  f32x4   __attribute__((ext_vector_type(4)));
typedef float  f32x16  __attribute__((ext_vector_type(16)));
typedef short  bf16x8  __attribute__((ext_vector_type(8)));

__device__ inline float bf2f(unsigned int u) {
    union { unsigned int i; float f; } c; c.i = u << 16; return c.f;
}
__device__ inline unsigned short f2bf(float f) {
    union { float f; unsigned int i; } c; c.f = f;
    unsigned int r = c.i + 0x7fffu + ((c.i >> 16) & 1u);   // RNE
    return (unsigned short)(r >> 16);
}

// ---------------- Kernel A: h = bf16(x @ W^T + b), plus sq[row] = ||h_row||^2 ----
// W in LDS as W5[d4][ei][eb^d4] (k-chunk major + XOR): compute-loop reads are
// lane-CONSECUTIVE (conflict-free). Old [128][136] layout was a 16-way bank
// conflict on every W read (bank stride 272 % 32 == 16) — the unmeasured suspect.
#define KA_ROWS 32
__global__ __launch_bounds__(256) void proj_kernel(
    const float* __restrict__ x, const float* __restrict__ W,
    const float* __restrict__ bias, unsigned short* __restrict__ h,
    float* __restrict__ sq)
{
    __shared__ __align__(16) unsigned short W5[32 * 4 * 32 * 4]; // 32 KiB
    __shared__ float xs[KA_ROWS][132];
    const int t = threadIdx.x;
    const long r0 = (long)blockIdx.x * KA_ROWS;

    // stage W: coalesced global float4 reads; LDS write addr = d4*256 + ei*64 + (eb^d4)*4
    for (int q = t; q < 4096; q += 256) {
        float4 w4 = ((const float4*)W)[q];
        int e = q >> 5, d4 = q & 31;
        int eb = e >> 2, ei = e & 3;
        ushort4 o;
        o.x = f2bf(w4.x); o.y = f2bf(w4.y); o.z = f2bf(w4.z); o.w = f2bf(w4.w);
        *(ushort4*)&W5[d4 * 256 + ei * 64 + ((eb ^ d4) & 31) * 4] = o;
    }
    const float4* xsrc = (const float4*)(x + r0 * 128);
    for (int q = t; q < KA_ROWS * 32; q += 256) {
        float4 v = xsrc[q];
        int r = q >> 5, d = (q & 31) << 2;
        xs[r][d] = v.x; xs[r][d + 1] = v.y; xs[r][d + 2] = v.z; xs[r][d + 3] = v.w;
    }
    __syncthreads();

    const int eb = t & 31, rb = t >> 5;
    const int e0 = eb * 4, rr0 = rb * 4;

    float acc_[4][4];
    #pragma unroll
    for (int ei = 0; ei < 4; ++ei) {
        float bv = bias[e0 + ei];
        #pragma unroll
        for (int ri = 0; ri < 4; ++ri) acc_[ri][ei] = bv;
    }

    for (int d4 = 0; d4 < 32; ++d4) {
        float wv[4][4];
        #pragma unroll
        for (int ei = 0; ei < 4; ++ei) {
            ushort4 u = *(const ushort4*)&W5[d4 * 256 + ei * 64 + ((eb ^ d4) & 31) * 4];
            wv[ei][0] = bf2f(u.x); wv[ei][1] = bf2f(u.y);
            wv[ei][2] = bf2f(u.z); wv[ei][3] = bf2f(u.w);
        }
        #pragma unroll
        for (int ri = 0; ri < 4; ++ri) {
            float4 xv = *(const float4*)&xs[rr0 + ri][d4 * 4];
            #pragma unroll
            for (int ei = 0; ei < 4; ++ei) {
                acc_[ri][ei] = fmaf(xv.x, wv[ei][0],
                               fmaf(xv.y, wv[ei][1],
                               fmaf(xv.z, wv[ei][2],
                               fmaf(xv.w, wv[ei][3], acc_[ri][ei]))));
            }
        }
    }

    float s[4] = {0.f, 0.f, 0.f, 0.f};
    #pragma unroll
    for (int ri = 0; ri < 4; ++ri) {
        ushort4 o;
        float v0 = bf2f(o.x = f2bf(acc_[ri][0]));
        float v1 = bf2f(o.y = f2bf(acc_[ri][1]));
        float v2 = bf2f(o.z = f2bf(acc_[ri][2]));
        float v3 = bf2f(o.w = f2bf(acc_[ri][3]));
        s[ri] = v0 * v0 + v1 * v1 + v2 * v2 + v3 * v3;
        *(ushort4*)&h[(r0 + rr0 + ri) * 128 + e0] = o;
    }
    #pragma unroll
    for (int ri = 0; ri < 4; ++ri) {
        #pragma unroll
        for (int m = 16; m > 0; m >>= 1) s[ri] += __shfl_xor(s[ri], m, 64);
    }
    if (eb == 0) {
        #pragma unroll
        for (int ri = 0; ri < 4; ++ri) sq[r0 + rr0 + ri] = s[ri];
    }
}

// ---------------- Kernel B: barrier-free gram + in-register transpose ---------
// R6 structure (wave-independent, 0 LDS, 0 barriers, 16 waves/CU), but the
// epilogue does a 4x4 lane-quad transpose (2 shfl_xor butterfly stages per
// reg-quad) so each lane stores 4 consecutive columns -> dwordx4 nt stores:
// 4 store instructions per js instead of 16 (store-issue-rate experiment).
__global__ __launch_bounds__(256, 4) void gram_kernel(
    const unsigned short* __restrict__ h, const float* __restrict__ sq,
    float* __restrict__ out)
{
    const int bid = blockIdx.x;                      // 1024 blocks
    const int xcd = bid & 7;
    const int bb  = xcd >> 1;                        // batch -> XCD pair
    const int local = ((xcd & 1) << 7) | (bid >> 3); // 0..255 within batch
    const int i0l = (local >> 1) * 32;               // i-strip (128 per batch)
    const int w = threadIdx.x >> 6, lane = threadIdx.x & 63;
    const int l31 = lane & 31, lh = lane >> 5, a = lane & 3;
    const int q4 = (l31 >> 2) << 2;                  // 4*q
    const int j0 = (local & 1) * 2048 + w * 512;     // wave's j-range
    const long jbase = (long)bb * 4096;
    const long ibase = jbase + i0l;
    const char* hb = (const char*)h;

    // A-fragments (32x32x16 A layout: row = lane&31, k-chunk = ks*2+lh)
    bf16x8 af[8];
    {
        const char* base = hb + ((ibase + l31) << 8);
        #pragma unroll
        for (int ks = 0; ks < 8; ++ks)
            af[ks] = *(const bf16x8*)(base + ((ks * 2 + lh) << 4));
    }
    // sq_i per accumulator register (C/D row = (reg&3)+8*(reg>>2)+4*lh)
    float sqi_r[16];
    #pragma unroll
    for (int reg = 0; reg < 16; ++reg)
        sqi_r[reg] = sq[ibase + (reg & 3) + 8 * (reg >> 2) + 4 * lh];

    for (int js = 0; js < 16; ++js) {
        const int jc0 = j0 + js * 32;                // wave's col base this step
        const int jc  = jc0 + l31;                   // this lane's col (local)
        const char* bp = hb + ((jbase + jc) << 8);
        bf16x8 bg[8];
        #pragma unroll
        for (int ks = 0; ks < 8; ++ks)
            bg[ks] = *(const bf16x8*)(bp + ((ks * 2 + lh) << 4));
        f32x16 acc = {};
        #pragma unroll
        for (int ks = 0; ks < 8; ++ks)
            acc = __builtin_amdgcn_mfma_f32_32x32x16_bf16(af[ks], bg[ks], acc, 0, 0, 0);

        // epilogue in place: val = exp(-sqrt(max(sqi+sqj-2g,0)))
        const float sqj = sq[jbase + jc];
        #pragma unroll
        for (int reg = 0; reg < 16; ++reg) {
            const int rl = (reg & 3) + 8 * (reg >> 2) + 4 * lh;
            float d2 = fmaxf(sqi_r[reg] + sqj - 2.0f * acc[reg], 0.0f);
            float val = __expf(-sqrtf(d2));
            if (i0l + rl == jc) val = 1.0f;          // exact diagonal
            acc[reg] = val;
        }

        // 4x4 transpose across lane-quads: after this, lane a of each quad
        // holds row 8k+a+4lh, cols 4q..4q+3 in acc[4k..4k+3].
        #pragma unroll
        for (int k = 0; k < 4; ++k) {
            // stage A: xor 2 — pairs (0,2),(1,3)
            { float s0 = (a & 2) ? acc[4*k+0] : acc[4*k+2];
              float r0 = __shfl_xor(s0, 2, 64);
              if (a & 2) acc[4*k+0] = r0; else acc[4*k+2] = r0;
              float s1 = (a & 2) ? acc[4*k+1] : acc[4*k+3];
              float r1 = __shfl_xor(s1, 2, 64);
              if (a & 2) acc[4*k+1] = r1; else acc[4*k+3] = r1; }
            // stage B: xor 1 — pairs (0,1),(2,3)
            { float s0 = (a & 1) ? acc[4*k+0] : acc[4*k+1];
              float r0 = __shfl_xor(s0, 1, 64);
              if (a & 1) acc[4*k+0] = r0; else acc[4*k+1] = r0;
              float s1 = (a & 1) ? acc[4*k+2] : acc[4*k+3];
              float r1 = __shfl_xor(s1, 1, 64);
              if (a & 1) acc[4*k+2] = r1; else acc[4*k+3] = r1; }
        }

        // 4 dwordx4 nt stores (16 B/lane, 128 B contiguous per 8-lane run)
        #pragma unroll
        for (int k = 0; k < 4; ++k) {
            f32x4 v = { acc[4*k+0], acc[4*k+1], acc[4*k+2], acc[4*k+3] };
            const int rl = 8 * k + a + 4 * lh;
            __builtin_nontemporal_store(
                v, (f32x4*)&out[((ibase + rl) << 12) + jc0 + q4]);
        }
    }
}

extern "C" void kernel_launch(void* const* d_in, const int* in_sizes, int n_in,
                              void* d_out, int out_size, void* d_ws, size_t ws_size,
                              hipStream_t stream) {
    const float* x = (const float*)d_in[0];   // [4,4096,128]
    const float* W = (const float*)d_in[1];   // [128,128]
    const float* b = (const float*)d_in[2];   // [128]
    float* out = (float*)d_out;               // [4,4096,4096]

    unsigned short* h = (unsigned short*)d_ws;                       // 16384*128 bf16
    float* sq = (float*)((char*)d_ws + (size_t)16384 * 128 * 2);     // 16384 fp32

    proj_kernel<<<dim3(16384 / KA_ROWS), dim3(256), 0, stream>>>(x, W, b, h, sq);
    gram_kernel<<<dim3(1024), dim3(256), 0, stream>>>(h, sq, out);
}

// Round 8
// 152.267 us; speedup vs baseline: 1.0695x; 1.0695x over previous
//
#include <hip/hip_runtime.h>

// B=4, N=4096, D=128 fixed by the reference setup.
// d_ws layout: [0, 4MiB) h as bf16 bits (ushort), [4MiB, +64KiB) sq fp32.

typedef float  f32x4   __attribute__((ext_vector_type(4)));
typedef short  bf16x8  __attribute__((ext_vector_type(8)));

__device__ inline float bf2f(unsigned int u) {
    union { unsigned int i; float f; } c; c.i = u << 16; return c.f;
}
__device__ inline unsigned short f2bf(float f) {
    union { float f; unsigned int i; } c; c.f = f;
    unsigned int r = c.i + 0x7fffu + ((c.i >> 16) & 1u);   // RNE
    return (unsigned short)(r >> 16);
}

// ---------------- Kernel A: h = bf16(x @ W^T + b), plus sq[row] = ||h_row||^2 ----
#define KA_ROWS 32
__global__ __launch_bounds__(256) void proj_kernel(
    const float* __restrict__ x, const float* __restrict__ W,
    const float* __restrict__ bias, unsigned short* __restrict__ h,
    float* __restrict__ sq)
{
    __shared__ __align__(16) unsigned short W5[32 * 4 * 32 * 4]; // 32 KiB
    __shared__ float xs[KA_ROWS][132];
    const int t = threadIdx.x;
    const long r0 = (long)blockIdx.x * KA_ROWS;

    for (int q = t; q < 4096; q += 256) {
        float4 w4 = ((const float4*)W)[q];
        int e = q >> 5, d4 = q & 31;
        int eb = e >> 2, ei = e & 3;
        ushort4 o;
        o.x = f2bf(w4.x); o.y = f2bf(w4.y); o.z = f2bf(w4.z); o.w = f2bf(w4.w);
        *(ushort4*)&W5[d4 * 256 + ei * 64 + ((eb ^ d4) & 31) * 4] = o;
    }
    const float4* xsrc = (const float4*)(x + r0 * 128);
    for (int q = t; q < KA_ROWS * 32; q += 256) {
        float4 v = xsrc[q];
        int r = q >> 5, d = (q & 31) << 2;
        xs[r][d] = v.x; xs[r][d + 1] = v.y; xs[r][d + 2] = v.z; xs[r][d + 3] = v.w;
    }
    __syncthreads();

    const int eb = t & 31, rb = t >> 5;
    const int e0 = eb * 4, rr0 = rb * 4;

    float acc_[4][4];
    #pragma unroll
    for (int ei = 0; ei < 4; ++ei) {
        float bv = bias[e0 + ei];
        #pragma unroll
        for (int ri = 0; ri < 4; ++ri) acc_[ri][ei] = bv;
    }

    for (int d4 = 0; d4 < 32; ++d4) {
        float wv[4][4];
        #pragma unroll
        for (int ei = 0; ei < 4; ++ei) {
            ushort4 u = *(const ushort4*)&W5[d4 * 256 + ei * 64 + ((eb ^ d4) & 31) * 4];
            wv[ei][0] = bf2f(u.x); wv[ei][1] = bf2f(u.y);
            wv[ei][2] = bf2f(u.z); wv[ei][3] = bf2f(u.w);
        }
        #pragma unroll
        for (int ri = 0; ri < 4; ++ri) {
            float4 xv = *(const float4*)&xs[rr0 + ri][d4 * 4];
            #pragma unroll
            for (int ei = 0; ei < 4; ++ei) {
                acc_[ri][ei] = fmaf(xv.x, wv[ei][0],
                               fmaf(xv.y, wv[ei][1],
                               fmaf(xv.z, wv[ei][2],
                               fmaf(xv.w, wv[ei][3], acc_[ri][ei]))));
            }
        }
    }

    float s[4] = {0.f, 0.f, 0.f, 0.f};
    #pragma unroll
    for (int ri = 0; ri < 4; ++ri) {
        ushort4 o;
        float v0 = bf2f(o.x = f2bf(acc_[ri][0]));
        float v1 = bf2f(o.y = f2bf(acc_[ri][1]));
        float v2 = bf2f(o.z = f2bf(acc_[ri][2]));
        float v3 = bf2f(o.w = f2bf(acc_[ri][3]));
        s[ri] = v0 * v0 + v1 * v1 + v2 * v2 + v3 * v3;
        *(ushort4*)&h[(r0 + rr0 + ri) * 128 + e0] = o;
    }
    #pragma unroll
    for (int ri = 0; ri < 4; ++ri) {
        #pragma unroll
        for (int m = 16; m > 0; m >>= 1) s[ri] += __shfl_xor(s[ri], m, 64);
    }
    if (eb == 0) {
        #pragma unroll
        for (int ri = 0; ri < 4; ++ri) sq[r0 + rr0 + ri] = s[ri];
    }
}

// ---------------- Kernel B: high-occupancy lean gram ----------------
// R7 counters: VALU 71%, MFMA 4%, FETCH 4 MB (reads solved), occupancy 2.8
// waves/SIMD (grid-limited). Fix: 16-row strips + 16x16x32 MFMA -> ~50 VGPR
// -> 8 waves/SIMD, 16384 waves; and a VALU diet: no transpose, diagonal
// hoisted out of the loop, inline-const fma, fast sqrt, block-uniform SGPR
// bases + 32-bit lane offsets so loop addressing folds into saddr+imm.
__global__ __launch_bounds__(256, 8) void gram_kernel(
    const unsigned short* __restrict__ h, const float* __restrict__ sq,
    float* __restrict__ out)
{
    const int bid = blockIdx.x;                       // 4096 blocks
    const int xcd = bid & 7;
    const int bb  = xcd >> 1;                         // batch -> XCD pair
    const int local = ((bid >> 3) << 1) | (xcd & 1);  // 0..1023 within batch
    const int i0l = (local >> 2) << 4;                // 16-row i-strip
    const int jq  = local & 3;                        // j quarter
    const int w = threadIdx.x >> 6, lane = threadIdx.x & 63;
    const int l15 = lane & 15, lq = lane >> 4;
    const int j0w = (jq << 10) + (w << 8);            // wave j start
    const long jbase = (long)bb << 12;
    const long ibase = jbase + i0l;
    const char* hb = (const char*)h;

    // A frags (16x16x32: row = lane&15, k-chunk = ks*4 + (lane>>4))
    bf16x8 af[4];
    {
        const char* base = hb + ((ibase + l15) << 8);
        #pragma unroll
        for (int ks = 0; ks < 4; ++ks)
            af[ks] = *(const bf16x8*)(base + ((ks * 4 + lq) << 4));
    }
    // sq_i per acc reg (C/D: row = (lane>>4)*4 + reg, col = lane&15)
    float sqi_r[4];
    #pragma unroll
    for (int reg = 0; reg < 4; ++reg)
        sqi_r[reg] = sq[ibase + lq * 4 + reg];

    float* ob = out + ((size_t)bb << 24) + ((size_t)i0l << 12); // block-uniform
    const float* sqj_b = sq + jbase;                            // block-uniform
    unsigned voff_st[4];
    #pragma unroll
    for (int reg = 0; reg < 4; ++reg)
        voff_st[reg] = (unsigned)((lq * 4 + reg) * 4096 + j0w + l15);

    const char* hj = hb + ((jbase + j0w + l15) << 8);  // +4096 B per js

    for (int js = 0; js < 16; ++js) {
        bf16x8 bg[4];
        #pragma unroll
        for (int ks = 0; ks < 4; ++ks)
            bg[ks] = *(const bf16x8*)(hj + ((ks * 4 + lq) << 4));
        f32x4 acc = {};
        #pragma unroll
        for (int ks = 0; ks < 4; ++ks)
            acc = __builtin_amdgcn_mfma_f32_16x16x32_bf16(af[ks], bg[ks], acc, 0, 0, 0);

        const float sqj = sqj_b[j0w + js * 16 + l15];
        #pragma unroll
        for (int reg = 0; reg < 4; ++reg) {
            float d2 = fmaxf(fmaf(acc[reg], -2.0f, sqi_r[reg] + sqj), 0.0f);
            float val = __expf(-__builtin_amdgcn_sqrtf(d2));
            __builtin_nontemporal_store(val, ob + voff_st[reg] + js * 16);
        }
        hj += 4096;
    }

    // exact diagonal: rewrite after all loop stores have drained
    if ((i0l & ~255) == j0w && lane < 16) {
        asm volatile("s_waitcnt vmcnt(0)" ::: "memory");
        __builtin_nontemporal_store(1.0f, ob + lane * 4096 + i0l + lane);
    }
}

extern "C" void kernel_launch(void* const* d_in, const int* in_sizes, int n_in,
                              void* d_out, int out_size, void* d_ws, size_t ws_size,
                              hipStream_t stream) {
    const float* x = (const float*)d_in[0];   // [4,4096,128]
    const float* W = (const float*)d_in[1];   // [128,128]
    const float* b = (const float*)d_in[2];   // [128]
    float* out = (float*)d_out;               // [4,4096,4096]

    unsigned short* h = (unsigned short*)d_ws;                       // 16384*128 bf16
    float* sq = (float*)((char*)d_ws + (size_t)16384 * 128 * 2);     // 16384 fp32

    proj_kernel<<<dim3(16384 / KA_ROWS), dim3(256), 0, stream>>>(x, W, b, h, sq);
    gram_kernel<<<dim3(4096), dim3(256), 0, stream>>>(h, sq, out);
}

// Round 9
// 88.248 us; speedup vs baseline: 1.8454x; 1.7254x over previous
//
#include <hip/hip_runtime.h>

// B=4, N=4096, D=128 fixed by the reference setup.
// d_ws layout: [0, 4MiB) h as bf16 bits (ushort), [4MiB, +64KiB) sq fp32.

typedef float  f32x4   __attribute__((ext_vector_type(4)));
typedef float  f32x16  __attribute__((ext_vector_type(16)));
typedef short  bf16x8  __attribute__((ext_vector_type(8)));
typedef __attribute__((address_space(3))) void       lds_void_t;
typedef const __attribute__((address_space(1))) void gvoid_t;

__device__ inline float bf2f(unsigned int u) {
    union { unsigned int i; float f; } c; c.i = u << 16; return c.f;
}
__device__ inline unsigned short f2bf(float f) {
    union { float f; unsigned int i; } c; c.f = f;
    unsigned int r = c.i + 0x7fffu + ((c.i >> 16) & 1u);   // RNE
    return (unsigned short)(r >> 16);
}

// ---------------- Kernel A: h = bf16(x @ W^T + b), plus sq[row] = ||h_row||^2 ----
// (R8 version: W in LDS k-chunk-major + XOR, conflict-free reads.)
#define KA_ROWS 32
__global__ __launch_bounds__(256) void proj_kernel(
    const float* __restrict__ x, const float* __restrict__ W,
    const float* __restrict__ bias, unsigned short* __restrict__ h,
    float* __restrict__ sq)
{
    __shared__ __align__(16) unsigned short W5[32 * 4 * 32 * 4]; // 32 KiB
    __shared__ float xs[KA_ROWS][132];
    const int t = threadIdx.x;
    const long r0 = (long)blockIdx.x * KA_ROWS;

    for (int q = t; q < 4096; q += 256) {
        float4 w4 = ((const float4*)W)[q];
        int e = q >> 5, d4 = q & 31;
        int eb = e >> 2, ei = e & 3;
        ushort4 o;
        o.x = f2bf(w4.x); o.y = f2bf(w4.y); o.z = f2bf(w4.z); o.w = f2bf(w4.w);
        *(ushort4*)&W5[d4 * 256 + ei * 64 + ((eb ^ d4) & 31) * 4] = o;
    }
    const float4* xsrc = (const float4*)(x + r0 * 128);
    for (int q = t; q < KA_ROWS * 32; q += 256) {
        float4 v = xsrc[q];
        int r = q >> 5, d = (q & 31) << 2;
        xs[r][d] = v.x; xs[r][d + 1] = v.y; xs[r][d + 2] = v.z; xs[r][d + 3] = v.w;
    }
    __syncthreads();

    const int eb = t & 31, rb = t >> 5;
    const int e0 = eb * 4, rr0 = rb * 4;

    float acc_[4][4];
    #pragma unroll
    for (int ei = 0; ei < 4; ++ei) {
        float bv = bias[e0 + ei];
        #pragma unroll
        for (int ri = 0; ri < 4; ++ri) acc_[ri][ei] = bv;
    }

    for (int d4 = 0; d4 < 32; ++d4) {
        float wv[4][4];
        #pragma unroll
        for (int ei = 0; ei < 4; ++ei) {
            ushort4 u = *(const ushort4*)&W5[d4 * 256 + ei * 64 + ((eb ^ d4) & 31) * 4];
            wv[ei][0] = bf2f(u.x); wv[ei][1] = bf2f(u.y);
            wv[ei][2] = bf2f(u.z); wv[ei][3] = bf2f(u.w);
        }
        #pragma unroll
        for (int ri = 0; ri < 4; ++ri) {
            float4 xv = *(const float4*)&xs[rr0 + ri][d4 * 4];
            #pragma unroll
            for (int ei = 0; ei < 4; ++ei) {
                acc_[ri][ei] = fmaf(xv.x, wv[ei][0],
                               fmaf(xv.y, wv[ei][1],
                               fmaf(xv.z, wv[ei][2],
                               fmaf(xv.w, wv[ei][3], acc_[ri][ei]))));
            }
        }
    }

    float s[4] = {0.f, 0.f, 0.f, 0.f};
    #pragma unroll
    for (int ri = 0; ri < 4; ++ri) {
        ushort4 o;
        float v0 = bf2f(o.x = f2bf(acc_[ri][0]));
        float v1 = bf2f(o.y = f2bf(acc_[ri][1]));
        float v2 = bf2f(o.z = f2bf(acc_[ri][2]));
        float v3 = bf2f(o.w = f2bf(acc_[ri][3]));
        s[ri] = v0 * v0 + v1 * v1 + v2 * v2 + v3 * v3;
        *(ushort4*)&h[(r0 + rr0 + ri) * 128 + e0] = o;
    }
    #pragma unroll
    for (int ri = 0; ri < 4; ++ri) {
        #pragma unroll
        for (int m = 16; m > 0; m >>= 1) s[ri] += __shfl_xor(s[ri], m, 64);
    }
    if (eb == 0) {
        #pragma unroll
        for (int ri = 0; ri < 4; ++ri) sq[r0 + rr0 + ri] = s[ri];
    }
}

// ---------------- Kernel B: 128x128 LDS-tile gram + XCD affinity ----------------
// R2/R3's proven structure (lowest reads/elem: 4 B via shared 128x128 tiles)
// with R4's proven XCD-affinity mapping (reads become L2 hits: each batch's
// 1 MiB h-panel pinned to an XCD pair). Conduit traffic: 268 MB L2 reads +
// 268 MB HBM writes — about 1.5x less than the ~100 µs club, 2.5x less than R8.
__global__ __launch_bounds__(256) void gram_kernel(
    const unsigned short* __restrict__ h, const float* __restrict__ sq,
    float* __restrict__ out)
{
    __shared__ __align__(16) unsigned short hs[2][128 * 128]; // 64 KiB
    const int bid = blockIdx.x;                       // 4096 blocks
    const int xcd = bid & 7;
    const int bb  = xcd >> 1;                         // batch -> XCD pair
    const int tloc = ((bid >> 3) << 1) | (xcd & 1);   // 0..1023 tile in batch
    const int it = tloc >> 5, jt = tloc & 31;
    const int i0 = bb * 4096 + it * 128;
    const int j0 = bb * 4096 + jt * 128;
    const int t = threadIdx.x, w = t >> 6, lane = t & 63;

    const char* hb = (const char*)h;
    #pragma unroll
    for (int q = 0; q < 8; ++q) {
        int p   = ((w * 8 + q) << 10) + (lane << 4);  // linear byte offset in tile
        int row = p >> 8;                              // 256 B per row
        int c   = (p >> 4) & 15;                       // 16 B chunk in row
        int cs  = c ^ (row & 15);                      // inverse swizzle at source
        const void* srcA = hb + ((long)(i0 + row) << 8) + (cs << 4);
        const void* srcB = hb + ((long)(j0 + row) << 8) + (cs << 4);
        unsigned off = (unsigned)((w * 8 + q) << 10);  // wave-uniform LDS base
        __builtin_amdgcn_global_load_lds((gvoid_t*)srcA,
            (lds_void_t*)(((char*)&hs[0][0]) + off), 16, 0, 0);
        __builtin_amdgcn_global_load_lds((gvoid_t*)srcB,
            (lds_void_t*)(((char*)&hs[1][0]) + off), 16, 0, 0);
    }
    __syncthreads();

    const int wr = w >> 1, wc = w & 1;      // wave -> 64x64 quadrant
    const int l31 = lane & 31, lh = lane >> 5;
    f32x16 acc[2][2] = {};
    const char* h0 = (const char*)&hs[0][0];
    const char* h1 = (const char*)&hs[1][0];

    #pragma unroll
    for (int ks = 0; ks < 8; ++ks) {        // K = 8 x 16
        bf16x8 af[2], bg[2];
        #pragma unroll
        for (int rb = 0; rb < 2; ++rb) {
            int rowA = wr * 64 + rb * 32 + l31;
            int cA = ((ks * 2 + lh) ^ (rowA & 15)) << 4;
            af[rb] = *(const bf16x8*)(h0 + (rowA << 8) + cA);
            int rowB = wc * 64 + rb * 32 + l31;
            int cB = ((ks * 2 + lh) ^ (rowB & 15)) << 4;
            bg[rb] = *(const bf16x8*)(h1 + (rowB << 8) + cB);
        }
        #pragma unroll
        for (int rb = 0; rb < 2; ++rb)
            #pragma unroll
            for (int nb = 0; nb < 2; ++nb)
                acc[rb][nb] = __builtin_amdgcn_mfma_f32_32x32x16_bf16(
                    af[rb], bg[nb], acc[rb][nb], 0, 0, 0);
    }

    // epilogue: d2 = sq_i + sq_j - 2*gram; out = exp(-sqrt(max(d2,0)))
    float sqj_r[2];
    #pragma unroll
    for (int nb = 0; nb < 2; ++nb) sqj_r[nb] = sq[j0 + wc * 64 + nb * 32 + l31];

    #pragma unroll
    for (int rb = 0; rb < 2; ++rb) {
        #pragma unroll
        for (int reg = 0; reg < 16; ++reg) {
            int il = wr * 64 + rb * 32 + (reg & 3) + 8 * (reg >> 2) + 4 * lh;
            float sqi_v = sq[i0 + il];
            #pragma unroll
            for (int nb = 0; nb < 2; ++nb) {
                int jl = wc * 64 + nb * 32 + l31;   // 32 consecutive cols in 32 lanes
                float g  = acc[rb][nb][reg];
                float d2 = fmaxf(sqi_v + sqj_r[nb] - 2.0f * g, 0.0f);
                float val = __expf(-sqrtf(d2));
                if (it == jt && il == jl) val = 1.0f;     // exact diagonal
                __builtin_nontemporal_store(
                    val, &out[((long)(i0 + il) << 12) + (jt << 7) + jl]);
            }
        }
    }
}

extern "C" void kernel_launch(void* const* d_in, const int* in_sizes, int n_in,
                              void* d_out, int out_size, void* d_ws, size_t ws_size,
                              hipStream_t stream) {
    const float* x = (const float*)d_in[0];   // [4,4096,128]
    const float* W = (const float*)d_in[1];   // [128,128]
    const float* b = (const float*)d_in[2];   // [128]
    float* out = (float*)d_out;               // [4,4096,4096]

    unsigned short* h = (unsigned short*)d_ws;                       // 16384*128 bf16
    float* sq = (float*)((char*)d_ws + (size_t)16384 * 128 * 2);     // 16384 fp32

    proj_kernel<<<dim3(16384 / KA_ROWS), dim3(256), 0, stream>>>(x, W, b, h, sq);
    gram_kernel<<<dim3(4096), dim3(256), 0, stream>>>(h, sq, out);
}

// Round 10
// 82.971 us; speedup vs baseline: 1.9628x; 1.0636x over previous
//
#include <hip/hip_runtime.h>

// B=4, N=4096, D=128 fixed by the reference setup.
// d_ws layout: [0, 4MiB) h as bf16 bits (ushort), [4MiB, +64KiB) sq fp32.

typedef float  f32x4   __attribute__((ext_vector_type(4)));
typedef float  f32x16  __attribute__((ext_vector_type(16)));
typedef short  bf16x8  __attribute__((ext_vector_type(8)));
typedef __attribute__((address_space(3))) void       lds_void_t;
typedef const __attribute__((address_space(1))) void gvoid_t;

__device__ inline float bf2f(unsigned int u) {
    union { unsigned int i; float f; } c; c.i = u << 16; return c.f;
}
__device__ inline unsigned short f2bf(float f) {
    union { float f; unsigned int i; } c; c.f = f;
    unsigned int r = c.i + 0x7fffu + ((c.i >> 16) & 1u);   // RNE
    return (unsigned short)(r >> 16);
}

// ---------------- Kernel A: h = bf16(x @ W^T + b), plus sq[row] = ||h_row||^2 ----
#define KA_ROWS 32
__global__ __launch_bounds__(256) void proj_kernel(
    const float* __restrict__ x, const float* __restrict__ W,
    const float* __restrict__ bias, unsigned short* __restrict__ h,
    float* __restrict__ sq)
{
    __shared__ __align__(16) unsigned short W5[32 * 4 * 32 * 4]; // 32 KiB
    __shared__ float xs[KA_ROWS][132];
    const int t = threadIdx.x;
    const long r0 = (long)blockIdx.x * KA_ROWS;

    for (int q = t; q < 4096; q += 256) {
        float4 w4 = ((const float4*)W)[q];
        int e = q >> 5, d4 = q & 31;
        int eb = e >> 2, ei = e & 3;
        ushort4 o;
        o.x = f2bf(w4.x); o.y = f2bf(w4.y); o.z = f2bf(w4.z); o.w = f2bf(w4.w);
        *(ushort4*)&W5[d4 * 256 + ei * 64 + ((eb ^ d4) & 31) * 4] = o;
    }
    const float4* xsrc = (const float4*)(x + r0 * 128);
    for (int q = t; q < KA_ROWS * 32; q += 256) {
        float4 v = xsrc[q];
        int r = q >> 5, d = (q & 31) << 2;
        xs[r][d] = v.x; xs[r][d + 1] = v.y; xs[r][d + 2] = v.z; xs[r][d + 3] = v.w;
    }
    __syncthreads();

    const int eb = t & 31, rb = t >> 5;
    const int e0 = eb * 4, rr0 = rb * 4;

    float acc_[4][4];
    #pragma unroll
    for (int ei = 0; ei < 4; ++ei) {
        float bv = bias[e0 + ei];
        #pragma unroll
        for (int ri = 0; ri < 4; ++ri) acc_[ri][ei] = bv;
    }

    for (int d4 = 0; d4 < 32; ++d4) {
        float wv[4][4];
        #pragma unroll
        for (int ei = 0; ei < 4; ++ei) {
            ushort4 u = *(const ushort4*)&W5[d4 * 256 + ei * 64 + ((eb ^ d4) & 31) * 4];
            wv[ei][0] = bf2f(u.x); wv[ei][1] = bf2f(u.y);
            wv[ei][2] = bf2f(u.z); wv[ei][3] = bf2f(u.w);
        }
        #pragma unroll
        for (int ri = 0; ri < 4; ++ri) {
            float4 xv = *(const float4*)&xs[rr0 + ri][d4 * 4];
            #pragma unroll
            for (int ei = 0; ei < 4; ++ei) {
                acc_[ri][ei] = fmaf(xv.x, wv[ei][0],
                               fmaf(xv.y, wv[ei][1],
                               fmaf(xv.z, wv[ei][2],
                               fmaf(xv.w, wv[ei][3], acc_[ri][ei]))));
            }
        }
    }

    float s[4] = {0.f, 0.f, 0.f, 0.f};
    #pragma unroll
    for (int ri = 0; ri < 4; ++ri) {
        ushort4 o;
        float v0 = bf2f(o.x = f2bf(acc_[ri][0]));
        float v1 = bf2f(o.y = f2bf(acc_[ri][1]));
        float v2 = bf2f(o.z = f2bf(acc_[ri][2]));
        float v3 = bf2f(o.w = f2bf(acc_[ri][3]));
        s[ri] = v0 * v0 + v1 * v1 + v2 * v2 + v3 * v3;
        *(ushort4*)&h[(r0 + rr0 + ri) * 128 + e0] = o;
    }
    #pragma unroll
    for (int ri = 0; ri < 4; ++ri) {
        #pragma unroll
        for (int m = 16; m > 0; m >>= 1) s[ri] += __shfl_xor(s[ri], m, 64);
    }
    if (eb == 0) {
        #pragma unroll
        for (int ri = 0; ri < 4; ++ri) sq[r0 + rr0 + ri] = s[ri];
    }
}

// ---------------- Kernel B: 256x256 LDS-tile gram + XCD affinity ----------------
// Conduit model (R9-validated): time ~ total L2+HBM bytes / ~9 TB/s.
// T=256 tile halves read traffic vs T=128: 2 B/elem -> 134 MB reads + 268 MB
// writes = 402 MB. 8 waves/block, 128 KiB LDS (2 x 64 KiB panels), each wave
// a 128x64 quadrant = 4x2 MFMA 32x32 blocks. Same swizzle + XCD affinity.
__global__ __launch_bounds__(512, 2) void gram_kernel(
    const unsigned short* __restrict__ h, const float* __restrict__ sq,
    float* __restrict__ out)
{
    __shared__ __align__(16) unsigned short hsI[256 * 128]; // 64 KiB
    __shared__ __align__(16) unsigned short hsJ[256 * 128]; // 64 KiB
    const int bid = blockIdx.x;                       // 1024 blocks
    const int xcd = bid & 7;
    const int bb  = xcd >> 1;                         // batch -> XCD pair
    const int tloc = ((bid >> 3) << 1) | (xcd & 1);   // 0..255 tile in batch
    const int it = tloc >> 4, jt = tloc & 15;
    const int i0 = bb * 4096 + it * 256;
    const int j0 = bb * 4096 + jt * 256;
    const int t = threadIdx.x, w = t >> 6, lane = t & 63;

    const char* hb = (const char*)h;
    #pragma unroll
    for (int q = 0; q < 8; ++q) {
        int p   = (q * 512 + t) << 4;                 // linear byte off in panel
        int row = p >> 8;                             // 256 B per row
        int c   = (p >> 4) & 15;
        int cs  = c ^ (row & 15);                     // inverse swizzle at source
        unsigned off = (unsigned)p;                   // wave-uniform + lane*16
        __builtin_amdgcn_global_load_lds(
            (gvoid_t*)(hb + ((long)(i0 + row) << 8) + (cs << 4)),
            (lds_void_t*)(((char*)hsI) + off), 16, 0, 0);
        __builtin_amdgcn_global_load_lds(
            (gvoid_t*)(hb + ((long)(j0 + row) << 8) + (cs << 4)),
            (lds_void_t*)(((char*)hsJ) + off), 16, 0, 0);
    }
    __syncthreads();

    const int wr = w >> 2, wc = w & 3;      // wave -> 128x64 quadrant
    const int l31 = lane & 31, lh = lane >> 5;
    f32x16 acc[4][2] = {};
    const char* hI = (const char*)hsI;
    const char* hJ = (const char*)hsJ;

    #pragma unroll
    for (int ks = 0; ks < 8; ++ks) {        // K = 8 x 16
        bf16x8 af[4], bg[2];
        #pragma unroll
        for (int rb = 0; rb < 4; ++rb) {
            int rowA = wr * 128 + rb * 32 + l31;
            int cA = ((ks * 2 + lh) ^ (rowA & 15)) << 4;
            af[rb] = *(const bf16x8*)(hI + (rowA << 8) + cA);
        }
        #pragma unroll
        for (int nb = 0; nb < 2; ++nb) {
            int rowB = wc * 64 + nb * 32 + l31;
            int cB = ((ks * 2 + lh) ^ (rowB & 15)) << 4;
            bg[nb] = *(const bf16x8*)(hJ + (rowB << 8) + cB);
        }
        #pragma unroll
        for (int rb = 0; rb < 4; ++rb)
            #pragma unroll
            for (int nb = 0; nb < 2; ++nb)
                acc[rb][nb] = __builtin_amdgcn_mfma_f32_32x32x16_bf16(
                    af[rb], bg[nb], acc[rb][nb], 0, 0, 0);
    }

    // epilogue: d2 = sq_i + sq_j - 2*gram; out = exp(-sqrt(max(d2,0)))
    float sqj_r[2];
    #pragma unroll
    for (int nb = 0; nb < 2; ++nb) sqj_r[nb] = sq[j0 + wc * 64 + nb * 32 + l31];

    #pragma unroll
    for (int rb = 0; rb < 4; ++rb) {
        #pragma unroll
        for (int reg = 0; reg < 16; ++reg) {
            int il = wr * 128 + rb * 32 + (reg & 3) + 8 * (reg >> 2) + 4 * lh;
            float sqi_v = sq[i0 + il];
            #pragma unroll
            for (int nb = 0; nb < 2; ++nb) {
                int jl = wc * 64 + nb * 32 + l31;
                float g  = acc[rb][nb][reg];
                float d2 = fmaxf(fmaf(g, -2.0f, sqi_v + sqj_r[nb]), 0.0f);
                float val = __expf(-sqrtf(d2));
                if (it == jt && il == jl) val = 1.0f;     // exact diagonal
                __builtin_nontemporal_store(
                    val, &out[((long)(i0 + il) << 12) + (jt << 8) + jl]);
            }
        }
    }
}

extern "C" void kernel_launch(void* const* d_in, const int* in_sizes, int n_in,
                              void* d_out, int out_size, void* d_ws, size_t ws_size,
                              hipStream_t stream) {
    const float* x = (const float*)d_in[0];   // [4,4096,128]
    const float* W = (const float*)d_in[1];   // [128,128]
    const float* b = (const float*)d_in[2];   // [128]
    float* out = (float*)d_out;               // [4,4096,4096]

    unsigned short* h = (unsigned short*)d_ws;                       // 16384*128 bf16
    float* sq = (float*)((char*)d_ws + (size_t)16384 * 128 * 2);     // 16384 fp32

    proj_kernel<<<dim3(16384 / KA_ROWS), dim3(256), 0, stream>>>(x, W, b, h, sq);
    gram_kernel<<<dim3(1024), dim3(512), 0, stream>>>(h, sq, out);
}